// Round 1
// baseline (352.345 us; speedup 1.0000x reference)
//
#include <hip/hip_runtime.h>
#include <hip/hip_bf16.h>

#define BSZ 8
#define SEQ 8192
#define DIM 128
#define NCH 128   // chunks per sequence
#define CLEN 64   // tokens per chunk

typedef unsigned short u16;
typedef unsigned int u32;
typedef short bf16x8 __attribute__((ext_vector_type(8)));
typedef float f32x4  __attribute__((ext_vector_type(4)));

__device__ __forceinline__ float us2f(u16 w){ union{u32 i;float f;}u; u.i=((u32)w)<<16; return u.f; }
__device__ __forceinline__ u16 f2us(float f){
  __hip_bfloat16 h = __float2bfloat16(f);
  union{ __hip_bfloat16 b; u16 s; }u; u.b=h; return u.s;
}
__device__ __forceinline__ float wred64(float v){
  #pragma unroll
  for (int o=1;o<64;o<<=1) v += __shfl_xor(v,o,64);
  return v;
}
__device__ __forceinline__ float red16(float v){
  v += __shfl_xor(v,1,64); v += __shfl_xor(v,2,64);
  v += __shfl_xor(v,4,64); v += __shfl_xor(v,8,64);
  return v;
}
__device__ __forceinline__ float sigmoidf_(float z){ return 1.f/(1.f+__expf(-z)); }
__device__ __forceinline__ float gelu_tanh(float x){
  float y = 0.7978845608028654f * fmaf(0.044715f*x, x*x, x);
  float e = __expf(2.f*y);
  float th = 1.f - 2.f/(e+1.f);
  return 0.5f*x*(1.f+th);
}
// wave-local LDS ordering: all prior ds_writes visible before subsequent ds_reads.
// (stripes are wave-private; no cross-wave barrier needed)
__device__ __forceinline__ void lds_fence(){
  asm volatile("s_waitcnt lgkmcnt(0)" ::: "memory");
  __builtin_amdgcn_sched_barrier(0);
}

// ---------------------------------------------------------------- K0: affines
__global__ __launch_bounds__(64) void k_aff(
    const float* __restrict__ c,
    const float* w0,const float* w1,const float* w2,const float* w3,const float* w4,const float* w5,
    const float* s0,const float* s1,const float* s2,const float* s3,const float* s4,const float* s5,
    float* __restrict__ aff)
{
  const float* ws[6]={w0,w1,w2,w3,w4,w5};
  const float* bs[6]={s0,s1,s2,s3,s4,s5};
  int l = threadIdx.x;
  for (int b=0;b<BSZ;++b){
    #pragma unroll
    for (int h=0;h<6;++h){
      float v = c[b*128+l]*ws[h][l] + c[b*128+64+l]*ws[h][64+l];
      v = wred64(v);
      if (l==0) aff[b*6+h] = v + bs[h][0];
    }
  }
}

// ---------------- K0b: pack weights into MFMA B-fragment-linear order (bf16)
// fragment fi = ((c*NB + n)*2 + k2)*64 + lane ; element j (0..7):
//   W[c*64 + k2*32 + (lane>>4)*8 + j][n*16 + (lane&15)]
// so a wave's B-load for (c,n,k2) is 64 consecutive 16B chunks (1KB coalesced).
__device__ __forceinline__ void pack_one(const float* __restrict__ W, int N,
                                         u16* __restrict__ out, int fi)
{
  int lane = fi & 63;
  int k2   = (fi >> 6) & 1;
  int cn   = fi >> 7;             // c*NB + n
  int NB   = N >> 4;
  int n    = cn % NB, c = cn / NB;
  int k0   = c*64 + k2*32 + (lane>>4)*8;
  int col  = n*16 + (lane&15);
  u16* o = out + (size_t)fi*8;
  #pragma unroll
  for (int j=0;j<8;++j) o[j] = f2us(W[(size_t)(k0+j)*N + col]);
}

__global__ __launch_bounds__(256) void k_prep(
    const float* __restrict__ w1, const float* __restrict__ w2, const float* __restrict__ wo,
    const float* __restrict__ win, const float* __restrict__ wi, const float* __restrict__ wr,
    u16* __restrict__ w1t, u16* __restrict__ w2t, u16* __restrict__ wot,
    u16* __restrict__ wint, u16* __restrict__ wit, u16* __restrict__ wrt)
{
  int i = blockIdx.x*256 + threadIdx.x;   // 104*256 = 26624 threads
  if      (i <  8192) pack_one(w1, 512, w1t, i);          // K=128,N=512
  else if (i < 16384) pack_one(w2, 128, w2t, i-8192);     // K=512,N=128
  else if (i < 20480) pack_one(wo, 128, wot, i-16384);    // K=256,N=128
  else if (i < 22528) pack_one(win,128, wint,i-20480);    // K=128,N=128
  else if (i < 24576) pack_one(wi, 128, wit, i-22528);
  else                pack_one(wr, 128, wrt, i-24576);
}

// -------------------- K1: LN + MFMA gates -> packed (a|b) + chunk summaries
// A_l stripes are wave-private; weights come straight from L2 (packed frags).
// Barriers: only ONE __syncthreads (before the cross-wave chunk scans).
__global__ __launch_bounds__(256,3) void k_pre(
    const float* __restrict__ xg, const u16* __restrict__ wint, const float* __restrict__ b_in,
    const float* __restrict__ pos, const u16* __restrict__ wit, const float* __restrict__ b_i,
    const u16* __restrict__ wrt, const float* __restrict__ b_r, const float* __restrict__ avec,
    const float* __restrict__ aff,
    u32* __restrict__ abg,
    float* __restrict__ Ag, float* __restrict__ Bfg, float* __restrict__ Bbg)
{
  __shared__ u16 A_l[CLEN*136];   // 17.4 KB: lnh, then u (A-operand layout)
  __shared__ u32 abp[CLEN*DIM];   // 32 KB: packed (a_bf16 | b_bf16<<16)
  const int t  = threadIdx.x;
  const int b  = blockIdx.x >> 7;
  const int ck = blockIdx.x & (NCH-1);
  const size_t base = ((size_t)(b*SEQ + ck*CLEN))*DIM;
  const int lane=t&63, wv=t>>6, col=lane&15, quad=lane>>4;
  const int m0 = wv*16;

  // LN: lnh = z * (1+s1)*rsqrt((1+s1)^2 * v/(v+eps) + eps), z=(x-m)*rsqrt(v+eps)
  {
    const float s1p = 1.f + aff[b*6+0];
    const int ln = t&63;
    for (int i=0;i<16;++i){
      int r = wv*16 + i;
      float2 v = *(const float2*)(xg + base + (size_t)r*DIM + 2*ln);
      float m  = wred64(v.x+v.y)*(1.f/128.f);
      float d0=v.x-m, d1=v.y-m;
      float var = wred64(d0*d0+d1*d1)*(1.f/128.f);
      float rs = rsqrtf(var + 1e-6f);
      float vz = var*rs*rs;
      float tt2 = s1p*rsqrtf(fmaf(s1p*s1p, vz, 1e-6f));
      float sc = rs*tt2;
      u32 pk = (u32)f2us(d0*sc) | ((u32)f2us(d1*sc)<<16);
      *(u32*)&A_l[r*136 + 2*ln] = pk;
    }
  }
  lds_fence();   // LN writes (cross-lane, same wave) -> A reads

  // ---- mm B: u = lnh @ w_in (B direct from global, fragment-packed) ----
  f32x4 uacc[8];
  #pragma unroll
  for (int n=0;n<8;++n) uacc[n]=(f32x4){0.f,0.f,0.f,0.f};
  #pragma unroll
  for (int c=0;c<2;++c){
    #pragma unroll
    for (int k2=0;k2<2;++k2){
      bf16x8 av = *(const bf16x8*)&A_l[(m0+col)*136 + c*64 + k2*32 + quad*8];
      #pragma unroll
      for (int n=0;n<8;++n){
        bf16x8 bv = *(const bf16x8*)&wint[(size_t)(((c*8+n)*2+k2)*64+lane)*8];
        uacc[n] = __builtin_amdgcn_mfma_f32_16x16x32_bf16(av, bv, uacc[n], 0,0,0);
      }
    }
  }
  float u_c[8][4];
  #pragma unroll
  for (int n=0;n<8;++n){
    int nc = n*16 + col;
    float bi = b_in[nc];
    #pragma unroll
    for (int r=0;r<4;++r){
      int row = m0 + quad*4 + r;
      u_c[n][r] = uacc[n][r] + bi + pos[(size_t)(ck*CLEN+row)*DIM + nc];
    }
  }
  // write u (bf16) into A_l (own wave's 16-row stripe)
  #pragma unroll
  for (int n=0;n<8;++n){
    #pragma unroll
    for (int r=0;r<4;++r)
      A_l[(m0+quad*4+r)*136 + n*16+col] = f2us(u_c[n][r]);
  }
  lds_fence();   // u writes -> mm C/D A-reads (same wave)

  // ---- mm C+D fused: gi, gr (shared A-fragment reads) ----
  f32x4 gacc[8], racc[8];
  #pragma unroll
  for (int n=0;n<8;++n){ gacc[n]=(f32x4){0.f,0.f,0.f,0.f}; racc[n]=(f32x4){0.f,0.f,0.f,0.f}; }
  #pragma unroll
  for (int c=0;c<2;++c){
    #pragma unroll
    for (int k2=0;k2<2;++k2){
      bf16x8 av = *(const bf16x8*)&A_l[(m0+col)*136 + c*64 + k2*32 + quad*8];
      #pragma unroll
      for (int n=0;n<8;++n){
        bf16x8 bgi = *(const bf16x8*)&wit[(size_t)(((c*8+n)*2+k2)*64+lane)*8];
        gacc[n] = __builtin_amdgcn_mfma_f32_16x16x32_bf16(av, bgi, gacc[n], 0,0,0);
        bf16x8 bgr = *(const bf16x8*)&wrt[(size_t)(((c*8+n)*2+k2)*64+lane)*8];
        racc[n] = __builtin_amdgcn_mfma_f32_16x16x32_bf16(av, bgr, racc[n], 0,0,0);
      }
    }
  }

  // a_t, b_t -> packed LDS + packed global (u32)
  #pragma unroll
  for (int n=0;n<8;++n){
    int nc = n*16 + col;
    float la = __logf(avec[nc]);
    float br = b_r[nc];
    float bi = b_i[nc];
    #pragma unroll
    for (int r=0;r<4;++r){
      int row = m0 + quad*4 + r;
      float gi = sigmoidf_(gacc[n][r]+bi);
      float g  = sigmoidf_(racc[n][r]+br);
      float a  = __expf(8.f*g*la);
      float bb = sqrtf(fmaxf(1.f-a*a,0.f))*gi*u_c[n][r];
      u32 pk = (u32)f2us(a) | ((u32)f2us(bb)<<16);
      abp[row*DIM+nc] = pk;
      abg[base + (size_t)row*DIM + nc] = pk;
    }
  }
  __syncthreads();   // abp is read cross-wave by the scans

  // chunk-local scans (over bf16 a,b -> consistent with k_scan) -> summaries
  const int sbase = (b*NCH+ck)*DIM;
  if (t < 128){
    float h=0.f, p=1.f;
    #pragma unroll 4
    for (int tt=0;tt<CLEN;++tt){
      u32 v=abp[tt*DIM+t];
      float a=us2f((u16)v), bb=us2f((u16)(v>>16));
      h=fmaf(a,h,bb); p*=a;
    }
    Ag[sbase+t]=p; Bfg[sbase+t]=h;
  } else {
    int ch=t-128; float h=0.f;
    #pragma unroll 4
    for (int tt=CLEN-1;tt>=0;--tt){
      u32 v=abp[tt*DIM+ch];
      h=fmaf(us2f((u16)v),h,us2f((u16)(v>>16)));
    }
    Bbg[sbase+ch]=h;
  }
}

// ------------------------------------------------ K2: prefix over chunk summaries
__global__ __launch_bounds__(128) void k_chunkscan(
    const float* __restrict__ Ag, const float* __restrict__ Bfg, const float* __restrict__ Bbg,
    float* __restrict__ Hf, float* __restrict__ Hb)
{
  const int dir = blockIdx.x >> 3, b = blockIdx.x & 7, ch = threadIdx.x;
  float s = 0.f;
  if (dir==0){
    for (int c=0;c<NCH;++c){ size_t i=((size_t)(b*NCH+c))*DIM+ch; Hf[i]=s; s=fmaf(Ag[i],s,Bfg[i]); }
  } else {
    for (int c=NCH-1;c>=0;--c){ size_t i=((size_t)(b*NCH+c))*DIM+ch; Hb[i]=s; s=fmaf(Ag[i],s,Bbg[i]); }
  }
}

// -------------------- K3: load packed a,b + seeded scan + MFMA out-proj + residual
// Barriers: 2 (after ab staging, after hcat scan). B from global packed frags.
__global__ __launch_bounds__(256,2) void k_scan(
    const u32* __restrict__ abg,
    const float* __restrict__ Hf, const float* __restrict__ Hb,
    const float* __restrict__ xg, const u16* __restrict__ wot, const float* __restrict__ b_out,
    const float* __restrict__ aff, float* __restrict__ outg)
{
  __shared__ u32 ab_l[CLEN*DIM];    // 32 KB packed (a|b)
  __shared__ u16 hcat[CLEN*264];    // 33.8 KB
  const int t  = threadIdx.x;
  const int b  = blockIdx.x >> 7;
  const int ck = blockIdx.x & (NCH-1);
  const size_t base = ((size_t)(b*SEQ + ck*CLEN))*DIM;

  {
    const uint4* src=(const uint4*)(abg+base);
    for (int i=t;i<2048;i+=256) ((uint4*)ab_l)[i]=src[i];
  }
  __syncthreads();

  // seeded scans -> hcat
  const int pbase=(b*NCH+ck)*DIM;
  if (t<128){
    float h=Hf[pbase+t];
    #pragma unroll 4
    for (int tt=0;tt<CLEN;++tt){
      u32 v=ab_l[tt*DIM+t];
      h=fmaf(us2f((u16)v),h,us2f((u16)(v>>16)));
      hcat[tt*264+t]=f2us(h);
    }
  } else {
    int ch=t-128;
    float h=Hb[pbase+ch];
    #pragma unroll 4
    for (int tt=CLEN-1;tt>=0;--tt){
      u32 v=ab_l[tt*DIM+ch];
      h=fmaf(us2f((u16)v),h,us2f((u16)(v>>16)));
      hcat[tt*264+128+ch]=f2us(h);
    }
  }
  __syncthreads();

  // MFMA out-proj: C[64][128] = hcat[64][256] @ w_out[256][128]
  const int lane=t&63, wv=t>>6, col=lane&15, quad=lane>>4;
  const int m0 = wv*16;
  f32x4 acc[8];
  #pragma unroll
  for (int n=0;n<8;++n) acc[n]=(f32x4){0.f,0.f,0.f,0.f};
  #pragma unroll
  for (int chk=0; chk<4; ++chk){      // K-chunks of 64
    #pragma unroll
    for (int k2=0;k2<2;++k2){
      bf16x8 av = *(const bf16x8*)&hcat[(m0+col)*264 + chk*64 + k2*32 + quad*8];
      #pragma unroll
      for (int n=0;n<8;++n){
        bf16x8 bv = *(const bf16x8*)&wot[(size_t)(((chk*8+n)*2+k2)*64+lane)*8];
        acc[n] = __builtin_amdgcn_mfma_f32_16x16x32_bf16(av, bv, acc[n], 0,0,0);
      }
    }
  }
  const float g1=aff[b*6+2];
  #pragma unroll
  for (int n=0;n<8;++n){
    int nc = n*16 + col;
    float bo = b_out[nc];
    #pragma unroll
    for (int r=0;r<4;++r){
      int row = m0 + quad*4 + r;
      size_t gi = base + (size_t)row*DIM + nc;
      outg[gi] = fmaf(g1, acc[n][r]+bo, xg[gi]);
    }
  }
}

// -------------------- K4: cLN2 + fused MFMA gelu MLP + gated residual
// ALL LDS is wave-private 16-row stripes -> ZERO __syncthreads.
// Weights direct from global packed frags (L2-resident, no staging barriers).
__global__ __launch_bounds__(256,3) void k_mlp(
    const u16* __restrict__ w1t, const float* __restrict__ b1v,
    const u16* __restrict__ w2t, const float* __restrict__ b2v,
    const float* __restrict__ aff, float* __restrict__ outg)
{
  __shared__ u16 h2l[CLEN*136];   // 17.4 KB: h2 (A-operand)
  __shared__ u16 m1p[CLEN*136];   // 17.4 KB: gelu panel (A-operand for mm2)
  const int t=threadIdx.x;
  const int b=blockIdx.x>>7;
  const size_t base=(size_t)blockIdx.x*CLEN*DIM;
  const int lane=t&63, wv=t>>6, col=lane&15, quad=lane>>4;
  const int m0 = wv*16;
  const float s2p=1.f+aff[b*6+3], b2a=aff[b*6+4], g2=aff[b*6+5];

  // step 0: h2 = (1+s2)*LN(x1)+b2 -> h2l (bf16); rows (t>>4)*4.. are wave-private
  {
    const int cg=t&15, rg=t>>4, j0=cg*8, r0=rg*4;
    #pragma unroll
    for (int ii=0;ii<4;++ii){
      int r=r0+ii;
      const float* xo = outg + base + (size_t)r*DIM + j0;
      float4 a = *(const float4*)xo;
      float4 bq = *(const float4*)(xo+4);
      float o[8]={a.x,a.y,a.z,a.w,bq.x,bq.y,bq.z,bq.w};
      float s=0.f;
      #pragma unroll
      for (int j=0;j<8;++j) s+=o[j];
      s=red16(s); float m=s*(1.f/128.f);
      float q2=0.f;
      #pragma unroll
      for (int j=0;j<8;++j){ float d=o[j]-m; q2+=d*d; }
      q2=red16(q2); float rs=rsqrtf(q2*(1.f/128.f)+1e-6f);
      u32 pk[4];
      #pragma unroll
      for (int q=0;q<4;++q){
        float a0=fmaf((o[2*q]-m)*rs,   s2p, b2a);
        float a1=fmaf((o[2*q+1]-m)*rs, s2p, b2a);
        pk[q]= (u32)f2us(a0) | ((u32)f2us(a1)<<16);
      }
      *(uint4*)&h2l[r*136+j0] = make_uint4(pk[0],pk[1],pk[2],pk[3]);
    }
  }
  lds_fence();   // LN writes -> mm1 A-reads (same wave, cross-lane)

  f32x4 acc2[8];
  #pragma unroll
  for (int n=0;n<8;++n) acc2[n]=(f32x4){0.f,0.f,0.f,0.f};

  #pragma unroll
  for (int p=0;p<4;++p){              // panels: 128 cols of m1 == 128 K-rows of mm2
    // ---- mm1 panel: C1p[64][128] = h2[64][128] @ w1[:,p*128:(p+1)*128] ----
    f32x4 accp[8];
    #pragma unroll
    for (int n=0;n<8;++n) accp[n]=(f32x4){0.f,0.f,0.f,0.f};
    #pragma unroll
    for (int c=0;c<2;++c){
      #pragma unroll
      for (int k2=0;k2<2;++k2){
        bf16x8 av = *(const bf16x8*)&h2l[(m0+col)*136 + c*64 + k2*32 + quad*8];
        #pragma unroll
        for (int n=0;n<8;++n){
          bf16x8 bv = *(const bf16x8*)&w1t[(size_t)(((c*32 + p*8+n)*2+k2)*64+lane)*8];
          accp[n] = __builtin_amdgcn_mfma_f32_16x16x32_bf16(av, bv, accp[n], 0,0,0);
        }
      }
    }
    // fence: previous panel's mm2 reads of m1p must complete before overwriting
    lds_fence();
    // gelu -> m1p (own wave's 16-row stripe)
    #pragma unroll
    for (int n=0;n<8;++n){
      int nc = n*16 + col;
      float bb = b1v[p*128 + nc];
      #pragma unroll
      for (int r=0;r<4;++r)
        m1p[(m0+quad*4+r)*136 + nc] = f2us(gelu_tanh(accp[n][r] + bb));
    }
    lds_fence();   // gelu writes -> mm2 A-reads (same wave, cross-lane)
    // ---- mm2 partial: acc2 += m1p[64][128] @ w2[p*128:(p+1)*128, :] ----
    #pragma unroll
    for (int c=0;c<2;++c){
      #pragma unroll
      for (int k2=0;k2<2;++k2){
        bf16x8 av = *(const bf16x8*)&m1p[(m0+col)*136 + c*64 + k2*32 + quad*8];
        #pragma unroll
        for (int n=0;n<8;++n){
          bf16x8 bv = *(const bf16x8*)&w2t[(size_t)((((p*2+c)*8+n)*2+k2)*64+lane)*8];
          acc2[n] = __builtin_amdgcn_mfma_f32_16x16x32_bf16(av, bv, acc2[n], 0,0,0);
        }
      }
    }
  }
  // epilogue: out = x1 + g2*(C2 + b2)
  #pragma unroll
  for (int n=0;n<8;++n){
    int nc = n*16 + col;
    float bb = b2v[nc];
    #pragma unroll
    for (int r=0;r<4;++r){
      int row = m0 + quad*4 + r;
      size_t gi = base + (size_t)row*DIM + nc;
      outg[gi] = fmaf(g2, acc2[n][r] + bb, outg[gi]);
    }
  }
}

// ----------------------------------------------------------------------------
extern "C" void kernel_launch(void* const* d_in, const int* in_sizes, int n_in,
                              void* d_out, int out_size, void* d_ws, size_t ws_size,
                              hipStream_t stream)
{
  (void)in_sizes; (void)n_in; (void)out_size; (void)ws_size;
  const float* x   =(const float*)d_in[0];
  const float* c   =(const float*)d_in[1];
  const float* c1sw=(const float*)d_in[2];  const float* c1sb=(const float*)d_in[3];
  const float* c1bw=(const float*)d_in[4];  const float* c1bb=(const float*)d_in[5];
  const float* g1w =(const float*)d_in[6];  const float* g1b =(const float*)d_in[7];
  const float* win =(const float*)d_in[8];  const float* binv=(const float*)d_in[9];
  const float* pos =(const float*)d_in[10];
  const float* wi  =(const float*)d_in[11]; const float* biv =(const float*)d_in[12];
  const float* wr  =(const float*)d_in[13]; const float* brv =(const float*)d_in[14];
  const float* av  =(const float*)d_in[15];
  const float* wout=(const float*)d_in[16]; const float* bout=(const float*)d_in[17];
  const float* c2sw=(const float*)d_in[18]; const float* c2sb=(const float*)d_in[19];
  const float* c2bw=(const float*)d_in[20]; const float* c2bb=(const float*)d_in[21];
  const float* g2w =(const float*)d_in[22]; const float* g2b =(const float*)d_in[23];
  const float* w1  =(const float*)d_in[24]; const float* b1v =(const float*)d_in[25];
  const float* w2  =(const float*)d_in[26]; const float* b2v =(const float*)d_in[27];

  // workspace layout (~36.6 MB total)
  float* wsf  = (float*)d_ws;
  float* Ag   = wsf;
  float* Bfg  = Ag   + 131072;
  float* Bbg  = Bfg  + 131072;
  float* Hf   = Bbg  + 131072;
  float* Hb   = Hf   + 131072;
  float* aff  = Hb   + 131072;       // 48 (pad 64)
  u16*   w1t  = (u16*)(aff + 64);    // 65536 u16, fragment-packed
  u16*   w2t  = w1t + 65536;         // 65536
  u16*   wot  = w2t + 65536;         // 32768
  u16*   wint = wot + 32768;         // 16384
  u16*   wit  = wint + 16384;
  u16*   wrt  = wit  + 16384;
  u32*   abg  = (u32*)(wrt + 16384); // [BSZ*SEQ*DIM] packed (a|b) = 33.5 MB

  float* outg = (float*)d_out;

  k_aff<<<dim3(1),dim3(64),0,stream>>>(c, c1sw,c1bw,g1w,c2sw,c2bw,g2w,
                                       c1sb,c1bb,g1b,c2sb,c2bb,g2b, aff);
  k_prep<<<dim3(104),dim3(256),0,stream>>>(w1,w2,wout,win,wi,wr,
                                           w1t,w2t,wot,wint,wit,wrt);
  k_pre<<<dim3(BSZ*NCH),dim3(256),0,stream>>>(x,wint,binv,pos,wit,biv,wrt,brv,av,aff,
                                              abg, Ag,Bfg,Bbg);
  k_chunkscan<<<dim3(16),dim3(128),0,stream>>>(Ag,Bfg,Bbg,Hf,Hb);
  k_scan<<<dim3(BSZ*NCH),dim3(256),0,stream>>>(abg,Hf,Hb,x,wot,bout,aff,outg);
  k_mlp<<<dim3(BSZ*NCH),dim3(256),0,stream>>>(w1t,b1v,w2t,b2v,aff,outg);
}

// Round 2
// 308.906 us; speedup vs baseline: 1.1406x; 1.1406x over previous
//
#include <hip/hip_runtime.h>
#include <hip/hip_bf16.h>

#define BSZ 8
#define SEQ 8192
#define DIM 128
#define NCH 128   // chunks per sequence
#define CLEN 64   // tokens per chunk

typedef unsigned short u16;
typedef unsigned int u32;
typedef short bf16x8 __attribute__((ext_vector_type(8)));
typedef float f32x4  __attribute__((ext_vector_type(4)));

__device__ __forceinline__ float us2f(u16 w){ union{u32 i;float f;}u; u.i=((u32)w)<<16; return u.f; }
__device__ __forceinline__ u16 f2us(float f){
  __hip_bfloat16 h = __float2bfloat16(f);
  union{ __hip_bfloat16 b; u16 s; }u; u.b=h; return u.s;
}
__device__ __forceinline__ float wred64(float v){
  #pragma unroll
  for (int o=1;o<64;o<<=1) v += __shfl_xor(v,o,64);
  return v;
}
__device__ __forceinline__ float red16(float v){
  v += __shfl_xor(v,1,64); v += __shfl_xor(v,2,64);
  v += __shfl_xor(v,4,64); v += __shfl_xor(v,8,64);
  return v;
}
__device__ __forceinline__ float sigmoidf_(float z){ return 1.f/(1.f+__expf(-z)); }
__device__ __forceinline__ float gelu_tanh(float x){
  float y = 0.7978845608028654f * fmaf(0.044715f*x, x*x, x);
  float e = __expf(2.f*y);
  float th = 1.f - 2.f/(e+1.f);
  return 0.5f*x*(1.f+th);
}
// wave-local LDS ordering: all prior ds ops complete before subsequent ones issue.
__device__ __forceinline__ void lds_fence(){
  asm volatile("s_waitcnt lgkmcnt(0)" ::: "memory");
  __builtin_amdgcn_sched_barrier(0);
}

// ---------------------------------------------------------------- K0: affines
__global__ __launch_bounds__(64) void k_aff(
    const float* __restrict__ c,
    const float* w0,const float* w1,const float* w2,const float* w3,const float* w4,const float* w5,
    const float* s0,const float* s1,const float* s2,const float* s3,const float* s4,const float* s5,
    float* __restrict__ aff)
{
  const float* ws[6]={w0,w1,w2,w3,w4,w5};
  const float* bs[6]={s0,s1,s2,s3,s4,s5};
  int l = threadIdx.x;
  for (int b=0;b<BSZ;++b){
    #pragma unroll
    for (int h=0;h<6;++h){
      float v = c[b*128+l]*ws[h][l] + c[b*128+64+l]*ws[h][64+l];
      v = wred64(v);
      if (l==0) aff[b*6+h] = v + bs[h][0];
    }
  }
}

// ---------------- K0b: pack weights into MFMA B-fragment-linear order (bf16)
// fragment fi = ((c*NB + n)*2 + k2)*64 + lane ; element j (0..7):
//   W[c*64 + k2*32 + (lane>>4)*8 + j][n*16 + (lane&15)]
// so a wave's B-load for (c,n,k2) is 64 consecutive 16B chunks (1KB coalesced).
__device__ __forceinline__ void pack_one(const float* __restrict__ W, int N,
                                         u16* __restrict__ out, int fi)
{
  int lane = fi & 63;
  int k2   = (fi >> 6) & 1;
  int cn   = fi >> 7;             // c*NB + n
  int NB   = N >> 4;
  int n    = cn % NB, c = cn / NB;
  int k0   = c*64 + k2*32 + (lane>>4)*8;
  int col  = n*16 + (lane&15);
  u16* o = out + (size_t)fi*8;
  #pragma unroll
  for (int j=0;j<8;++j) o[j] = f2us(W[(size_t)(k0+j)*N + col]);
}

__global__ __launch_bounds__(256) void k_prep(
    const float* __restrict__ w1, const float* __restrict__ w2, const float* __restrict__ wo,
    const float* __restrict__ win, const float* __restrict__ wi, const float* __restrict__ wr,
    u16* __restrict__ w1t, u16* __restrict__ w2t, u16* __restrict__ wot,
    u16* __restrict__ wint, u16* __restrict__ wit, u16* __restrict__ wrt)
{
  int i = blockIdx.x*256 + threadIdx.x;   // 104*256 = 26624 threads
  if      (i <  8192) pack_one(w1, 512, w1t, i);          // K=128,N=512
  else if (i < 16384) pack_one(w2, 128, w2t, i-8192);     // K=512,N=128
  else if (i < 20480) pack_one(wo, 128, wot, i-16384);    // K=256,N=128
  else if (i < 22528) pack_one(win,128, wint,i-20480);    // K=128,N=128
  else if (i < 24576) pack_one(wi, 128, wit, i-22528);
  else                pack_one(wr, 128, wrt, i-24576);
}

// -------------------- K1: LN + MFMA gates -> packed (a|b) + chunk summaries
// A_l stripes are wave-private; weights come straight from L1/L2 (packed frags).
__global__ __launch_bounds__(256,3) void k_pre(
    const float* __restrict__ xg, const u16* __restrict__ wint, const float* __restrict__ b_in,
    const float* __restrict__ pos, const u16* __restrict__ wit, const float* __restrict__ b_i,
    const u16* __restrict__ wrt, const float* __restrict__ b_r, const float* __restrict__ avec,
    const float* __restrict__ aff,
    u32* __restrict__ abg,
    float* __restrict__ Ag, float* __restrict__ Bfg, float* __restrict__ Bbg)
{
  __shared__ u16 A_l[CLEN*136];   // 17.4 KB: lnh, then u (A-operand layout)
  __shared__ u32 abp[CLEN*DIM];   // 32 KB: packed (a_bf16 | b_bf16<<16)
  const int t  = threadIdx.x;
  const int b  = blockIdx.x >> 7;
  const int ck = blockIdx.x & (NCH-1);
  const size_t base = ((size_t)(b*SEQ + ck*CLEN))*DIM;
  const int lane=t&63, wv=t>>6, col=lane&15, quad=lane>>4;
  const int m0 = wv*16;

  // LN: lnh = z * (1+s1)*rsqrt((1+s1)^2 * v/(v+eps) + eps), z=(x-m)*rsqrt(v+eps)
  {
    const float s1p = 1.f + aff[b*6+0];
    const int ln = t&63;
    for (int i=0;i<16;++i){
      int r = wv*16 + i;
      float2 v = *(const float2*)(xg + base + (size_t)r*DIM + 2*ln);
      float m  = wred64(v.x+v.y)*(1.f/128.f);
      float d0=v.x-m, d1=v.y-m;
      float var = wred64(d0*d0+d1*d1)*(1.f/128.f);
      float rs = rsqrtf(var + 1e-6f);
      float vz = var*rs*rs;
      float tt2 = s1p*rsqrtf(fmaf(s1p*s1p, vz, 1e-6f));
      float sc = rs*tt2;
      u32 pk = (u32)f2us(d0*sc) | ((u32)f2us(d1*sc)<<16);
      *(u32*)&A_l[r*136 + 2*ln] = pk;
    }
  }
  lds_fence();   // LN writes (cross-lane, same wave) -> A reads

  // ---- mm B: u = lnh @ w_in (B direct from global, fragment-packed) ----
  f32x4 uacc[8];
  #pragma unroll
  for (int n=0;n<8;++n) uacc[n]=(f32x4){0.f,0.f,0.f,0.f};
  #pragma unroll
  for (int c=0;c<2;++c){
    #pragma unroll
    for (int k2=0;k2<2;++k2){
      bf16x8 av = *(const bf16x8*)&A_l[(m0+col)*136 + c*64 + k2*32 + quad*8];
      #pragma unroll
      for (int n=0;n<8;++n){
        bf16x8 bv = *(const bf16x8*)&wint[(size_t)(((c*8+n)*2+k2)*64+lane)*8];
        uacc[n] = __builtin_amdgcn_mfma_f32_16x16x32_bf16(av, bv, uacc[n], 0,0,0);
      }
    }
  }
  float u_c[8][4];
  #pragma unroll
  for (int n=0;n<8;++n){
    int nc = n*16 + col;
    float bi = b_in[nc];
    #pragma unroll
    for (int r=0;r<4;++r){
      int row = m0 + quad*4 + r;
      u_c[n][r] = uacc[n][r] + bi + pos[(size_t)(ck*CLEN+row)*DIM + nc];
    }
  }
  // write u (bf16) into A_l (own wave's 16-row stripe)
  #pragma unroll
  for (int n=0;n<8;++n){
    #pragma unroll
    for (int r=0;r<4;++r)
      A_l[(m0+quad*4+r)*136 + n*16+col] = f2us(u_c[n][r]);
  }
  lds_fence();   // u writes -> mm C/D A-reads (same wave)

  // ---- mm C+D fused: gi, gr (shared A-fragment reads) ----
  f32x4 gacc[8], racc[8];
  #pragma unroll
  for (int n=0;n<8;++n){ gacc[n]=(f32x4){0.f,0.f,0.f,0.f}; racc[n]=(f32x4){0.f,0.f,0.f,0.f}; }
  #pragma unroll
  for (int c=0;c<2;++c){
    #pragma unroll
    for (int k2=0;k2<2;++k2){
      bf16x8 av = *(const bf16x8*)&A_l[(m0+col)*136 + c*64 + k2*32 + quad*8];
      #pragma unroll
      for (int n=0;n<8;++n){
        bf16x8 bgi = *(const bf16x8*)&wit[(size_t)(((c*8+n)*2+k2)*64+lane)*8];
        gacc[n] = __builtin_amdgcn_mfma_f32_16x16x32_bf16(av, bgi, gacc[n], 0,0,0);
        bf16x8 bgr = *(const bf16x8*)&wrt[(size_t)(((c*8+n)*2+k2)*64+lane)*8];
        racc[n] = __builtin_amdgcn_mfma_f32_16x16x32_bf16(av, bgr, racc[n], 0,0,0);
      }
    }
  }

  // a_t, b_t -> packed LDS + packed global (u32)
  #pragma unroll
  for (int n=0;n<8;++n){
    int nc = n*16 + col;
    float la = __logf(avec[nc]);
    float br = b_r[nc];
    float bi = b_i[nc];
    #pragma unroll
    for (int r=0;r<4;++r){
      int row = m0 + quad*4 + r;
      float gi = sigmoidf_(gacc[n][r]+bi);
      float g  = sigmoidf_(racc[n][r]+br);
      float a  = __expf(8.f*g*la);
      float bb = sqrtf(fmaxf(1.f-a*a,0.f))*gi*u_c[n][r];
      u32 pk = (u32)f2us(a) | ((u32)f2us(bb)<<16);
      abp[row*DIM+nc] = pk;
      abg[base + (size_t)row*DIM + nc] = pk;
    }
  }
  __syncthreads();   // abp is read cross-wave by the scans

  // chunk-local scans (over bf16 a,b -> consistent with k_scan) -> summaries
  const int sbase = (b*NCH+ck)*DIM;
  if (t < 128){
    float h=0.f, p=1.f;
    #pragma unroll 4
    for (int tt=0;tt<CLEN;++tt){
      u32 v=abp[tt*DIM+t];
      float a=us2f((u16)v), bb=us2f((u16)(v>>16));
      h=fmaf(a,h,bb); p*=a;
    }
    Ag[sbase+t]=p; Bfg[sbase+t]=h;
  } else {
    int ch=t-128; float h=0.f;
    #pragma unroll 4
    for (int tt=CLEN-1;tt>=0;--tt){
      u32 v=abp[tt*DIM+ch];
      h=fmaf(us2f((u16)v),h,us2f((u16)(v>>16)));
    }
    Bbg[sbase+ch]=h;
  }
}

// ------------------------------------------------ K2: prefix over chunk summaries
__global__ __launch_bounds__(128) void k_chunkscan(
    const float* __restrict__ Ag, const float* __restrict__ Bfg, const float* __restrict__ Bbg,
    float* __restrict__ Hf, float* __restrict__ Hb)
{
  const int dir = blockIdx.x >> 3, b = blockIdx.x & 7, ch = threadIdx.x;
  float s = 0.f;
  if (dir==0){
    for (int c=0;c<NCH;++c){ size_t i=((size_t)(b*NCH+c))*DIM+ch; Hf[i]=s; s=fmaf(Ag[i],s,Bfg[i]); }
  } else {
    for (int c=NCH-1;c>=0;--c){ size_t i=((size_t)(b*NCH+c))*DIM+ch; Hb[i]=s; s=fmaf(Ag[i],s,Bbg[i]); }
  }
}

// -------------------- K3: load packed a,b + seeded scan + MFMA out-proj + residual
__global__ __launch_bounds__(256,2) void k_scan(
    const u32* __restrict__ abg,
    const float* __restrict__ Hf, const float* __restrict__ Hb,
    const float* __restrict__ xg, const u16* __restrict__ wot, const float* __restrict__ b_out,
    const float* __restrict__ aff, float* __restrict__ outg)
{
  __shared__ u32 ab_l[CLEN*DIM];    // 32 KB packed (a|b)
  __shared__ u16 hcat[CLEN*264];    // 33.8 KB
  const int t  = threadIdx.x;
  const int b  = blockIdx.x >> 7;
  const int ck = blockIdx.x & (NCH-1);
  const size_t base = ((size_t)(b*SEQ + ck*CLEN))*DIM;

  {
    const uint4* src=(const uint4*)(abg+base);
    for (int i=t;i<2048;i+=256) ((uint4*)ab_l)[i]=src[i];
  }
  __syncthreads();

  // seeded scans -> hcat
  const int pbase=(b*NCH+ck)*DIM;
  if (t<128){
    float h=Hf[pbase+t];
    #pragma unroll 4
    for (int tt=0;tt<CLEN;++tt){
      u32 v=ab_l[tt*DIM+t];
      h=fmaf(us2f((u16)v),h,us2f((u16)(v>>16)));
      hcat[tt*264+t]=f2us(h);
    }
  } else {
    int ch=t-128;
    float h=Hb[pbase+ch];
    #pragma unroll 4
    for (int tt=CLEN-1;tt>=0;--tt){
      u32 v=ab_l[tt*DIM+ch];
      h=fmaf(us2f((u16)v),h,us2f((u16)(v>>16)));
      hcat[tt*264+128+ch]=f2us(h);
    }
  }
  __syncthreads();

  // MFMA out-proj: C[64][128] = hcat[64][256] @ w_out[256][128]
  const int lane=t&63, wv=t>>6, col=lane&15, quad=lane>>4;
  const int m0 = wv*16;
  f32x4 acc[8];
  #pragma unroll
  for (int n=0;n<8;++n) acc[n]=(f32x4){0.f,0.f,0.f,0.f};
  #pragma unroll
  for (int chk=0; chk<4; ++chk){      // K-chunks of 64
    #pragma unroll
    for (int k2=0;k2<2;++k2){
      bf16x8 av = *(const bf16x8*)&hcat[(m0+col)*264 + chk*64 + k2*32 + quad*8];
      #pragma unroll
      for (int n=0;n<8;++n){
        bf16x8 bv = *(const bf16x8*)&wot[(size_t)(((chk*8+n)*2+k2)*64+lane)*8];
        acc[n] = __builtin_amdgcn_mfma_f32_16x16x32_bf16(av, bv, acc[n], 0,0,0);
      }
    }
  }
  const float g1=aff[b*6+2];
  #pragma unroll
  for (int n=0;n<8;++n){
    int nc = n*16 + col;
    float bo = b_out[nc];
    #pragma unroll
    for (int r=0;r<4;++r){
      int row = m0 + quad*4 + r;
      size_t gi = base + (size_t)row*DIM + nc;
      outg[gi] = fmaf(g1, acc[n][r]+bo, xg[gi]);
    }
  }
}

// -------------------- K4: cLN2 + fused MFMA gelu MLP + gated residual
// N-split across waves: wave w owns mm1 output cols [w*128, w*128+128) ==
// mm2 K-rows [w*128, ...). B-fragments reused across an M-tile pair (1:2),
// gelu transpose buffer is wave-private (lds_fence only). Cross-wave f32
// K-reduction of mm2 partials through a 32KB LDS buffer overlaying h2l/m1t.
__global__ __launch_bounds__(256,2) void k_mlp(
    const u16* __restrict__ w1t, const float* __restrict__ b1v,
    const u16* __restrict__ w2t, const float* __restrict__ b2v,
    const float* __restrict__ aff, float* __restrict__ outg)
{
  __shared__ u16 smem[CLEN*136 + 4*2*16*136];   // 17408 + 17408 u16 = 34.8 KB
  u16* h2l = smem;                 // [64][136] LN output (A for mm1), cross-wave
  u16* m1t = smem + CLEN*136;      // per-wave: 2 tiles x [16][136] gelu scratch
  const int t=threadIdx.x;
  const int b=blockIdx.x>>7;
  const size_t base=(size_t)blockIdx.x*CLEN*DIM;
  const int lane=t&63, wv=t>>6, col=lane&15, quad=lane>>4;
  const float s2p=1.f+aff[b*6+3], b2a=aff[b*6+4], g2=aff[b*6+5];
  u16* mw = m1t + wv*(2*16*136);   // wave-private transpose scratch

  // step 0: h2 = (1+s2)*LN(x1)+b2 -> h2l (bf16)
  {
    const int cg=t&15, rg=t>>4, j0=cg*8, r0=rg*4;
    #pragma unroll
    for (int ii=0;ii<4;++ii){
      int r=r0+ii;
      const float* xo = outg + base + (size_t)r*DIM + j0;
      float4 a = *(const float4*)xo;
      float4 bq = *(const float4*)(xo+4);
      float o[8]={a.x,a.y,a.z,a.w,bq.x,bq.y,bq.z,bq.w};
      float s=0.f;
      #pragma unroll
      for (int j=0;j<8;++j) s+=o[j];
      s=red16(s); float m=s*(1.f/128.f);
      float q2=0.f;
      #pragma unroll
      for (int j=0;j<8;++j){ float d=o[j]-m; q2+=d*d; }
      q2=red16(q2); float rs=rsqrtf(q2*(1.f/128.f)+1e-6f);
      u32 pk[4];
      #pragma unroll
      for (int q=0;q<4;++q){
        float a0=fmaf((o[2*q]-m)*rs,   s2p, b2a);
        float a1=fmaf((o[2*q+1]-m)*rs, s2p, b2a);
        pk[q]= (u32)f2us(a0) | ((u32)f2us(a1)<<16);
      }
      *(uint4*)&h2l[r*136+j0] = make_uint4(pk[0],pk[1],pk[2],pk[3]);
    }
  }
  __syncthreads();   // h2l read cross-wave (all M-tiles by every wave)

  f32x4 acc2[4][8];  // full partial C2[64][128] for this wave's K-slice
  #pragma unroll
  for (int m=0;m<4;++m)
    #pragma unroll
    for (int n=0;n<8;++n) acc2[m][n]=(f32x4){0.f,0.f,0.f,0.f};

  #pragma unroll
  for (int mp=0;mp<2;++mp){           // M-tile pairs {0,1},{2,3}
    // ---- mm1: C1[pair rows][wave's 128 cols], n in 2 half-bursts of 4 ----
    #pragma unroll
    for (int h=0;h<2;++h){
      f32x4 a1[2][4];
      #pragma unroll
      for (int m=0;m<2;++m)
        #pragma unroll
        for (int n=0;n<4;++n) a1[m][n]=(f32x4){0.f,0.f,0.f,0.f};
      #pragma unroll
      for (int c=0;c<2;++c){
        #pragma unroll
        for (int k2=0;k2<2;++k2){
          bf16x8 av0 = *(const bf16x8*)&h2l[((2*mp+0)*16+col)*136 + c*64 + k2*32 + quad*8];
          bf16x8 av1 = *(const bf16x8*)&h2l[((2*mp+1)*16+col)*136 + c*64 + k2*32 + quad*8];
          #pragma unroll
          for (int n=0;n<4;++n){
            int ng = wv*8 + h*4 + n;   // global n-fragment (0..31)
            bf16x8 bv = *(const bf16x8*)&w1t[(size_t)(((c*32+ng)*2+k2)*64+lane)*8];
            a1[0][n] = __builtin_amdgcn_mfma_f32_16x16x32_bf16(av0, bv, a1[0][n], 0,0,0);
            a1[1][n] = __builtin_amdgcn_mfma_f32_16x16x32_bf16(av1, bv, a1[1][n], 0,0,0);
          }
        }
      }
      // prior mm2 reads of mw (previous pair) are done before overwrite
      lds_fence();
      // gelu + transpose into wave-private scratch (local cols 0..127)
      #pragma unroll
      for (int m=0;m<2;++m){
        #pragma unroll
        for (int n=0;n<4;++n){
          int lc = (h*4+n)*16 + col;           // local col 0..127
          float bb = b1v[wv*128 + lc];
          #pragma unroll
          for (int r=0;r<4;++r)
            mw[m*(16*136) + (quad*4+r)*136 + lc] = f2us(gelu_tanh(a1[m][n][r] + bb));
        }
      }
    }
    lds_fence();   // gelu writes -> mm2 A-reads (same wave)
    // ---- mm2 partial: acc2[pair] += m1[pair rows][wave K-slice] @ w2[slice][:]
    #pragma unroll
    for (int c2=0;c2<2;++c2){
      #pragma unroll
      for (int k2=0;k2<2;++k2){
        bf16x8 av0 = *(const bf16x8*)&mw[0*(16*136) + col*136 + c2*64 + k2*32 + quad*8];
        bf16x8 av1 = *(const bf16x8*)&mw[1*(16*136) + col*136 + c2*64 + k2*32 + quad*8];
        int cg = wv*2 + c2;                    // global K-chunk of w2 (0..7)
        #pragma unroll
        for (int n=0;n<8;++n){
          bf16x8 bv = *(const bf16x8*)&w2t[(size_t)(((cg*8+n)*2+k2)*64+lane)*8];
          acc2[2*mp+0][n] = __builtin_amdgcn_mfma_f32_16x16x32_bf16(av0, bv, acc2[2*mp+0][n], 0,0,0);
          acc2[2*mp+1][n] = __builtin_amdgcn_mfma_f32_16x16x32_bf16(av1, bv, acc2[2*mp+1][n], 0,0,0);
        }
      }
    }
  }
  __syncthreads();   // all mm2 done; smem is dead -> reuse as f32 pbuf

  // cross-wave K-reduction + epilogue, one M-tile (16 rows) per round
  float* pbuf = (float*)smem;        // [4 waves][16][128] f32 = 32 KB
  const int lrow = (lane>>4);        // 0..3
  const int cb   = (lane&15)*8;      // col block
  #pragma unroll
  for (int rt=0;rt<4;++rt){
    if (rt) __syncthreads();         // previous round's reads done
    #pragma unroll
    for (int n=0;n<8;++n){
      #pragma unroll
      for (int r=0;r<4;++r)
        pbuf[wv*2048 + (quad*4+r)*128 + n*16+col] = acc2[rt][n][r];
    }
    __syncthreads();
    // wave wv sums rows 4*wv..4*wv+3 of this tile across the 4 partials
    float s[8] = {0.f,0.f,0.f,0.f,0.f,0.f,0.f,0.f};
    #pragma unroll
    for (int p=0;p<4;++p){
      float4 x0 = *(const float4*)&pbuf[p*2048 + (4*wv+lrow)*128 + cb];
      float4 x1 = *(const float4*)&pbuf[p*2048 + (4*wv+lrow)*128 + cb + 4];
      s[0]+=x0.x; s[1]+=x0.y; s[2]+=x0.z; s[3]+=x0.w;
      s[4]+=x1.x; s[5]+=x1.y; s[6]+=x1.z; s[7]+=x1.w;
    }
    int grow = rt*16 + 4*wv + lrow;
    size_t gi = base + (size_t)grow*DIM + cb;
    float4 o0 = *(const float4*)&outg[gi];
    float4 o1 = *(const float4*)&outg[gi+4];
    float4 bb0 = *(const float4*)&b2v[cb];
    float4 bb1 = *(const float4*)&b2v[cb+4];
    float4 r0, r1;
    r0.x = fmaf(g2, s[0]+bb0.x, o0.x); r0.y = fmaf(g2, s[1]+bb0.y, o0.y);
    r0.z = fmaf(g2, s[2]+bb0.z, o0.z); r0.w = fmaf(g2, s[3]+bb0.w, o0.w);
    r1.x = fmaf(g2, s[4]+bb1.x, o1.x); r1.y = fmaf(g2, s[5]+bb1.y, o1.y);
    r1.z = fmaf(g2, s[6]+bb1.z, o1.z); r1.w = fmaf(g2, s[7]+bb1.w, o1.w);
    *(float4*)&outg[gi]   = r0;
    *(float4*)&outg[gi+4] = r1;
  }
}

// ----------------------------------------------------------------------------
extern "C" void kernel_launch(void* const* d_in, const int* in_sizes, int n_in,
                              void* d_out, int out_size, void* d_ws, size_t ws_size,
                              hipStream_t stream)
{
  (void)in_sizes; (void)n_in; (void)out_size; (void)ws_size;
  const float* x   =(const float*)d_in[0];
  const float* c   =(const float*)d_in[1];
  const float* c1sw=(const float*)d_in[2];  const float* c1sb=(const float*)d_in[3];
  const float* c1bw=(const float*)d_in[4];  const float* c1bb=(const float*)d_in[5];
  const float* g1w =(const float*)d_in[6];  const float* g1b =(const float*)d_in[7];
  const float* win =(const float*)d_in[8];  const float* binv=(const float*)d_in[9];
  const float* pos =(const float*)d_in[10];
  const float* wi  =(const float*)d_in[11]; const float* biv =(const float*)d_in[12];
  const float* wr  =(const float*)d_in[13]; const float* brv =(const float*)d_in[14];
  const float* av  =(const float*)d_in[15];
  const float* wout=(const float*)d_in[16]; const float* bout=(const float*)d_in[17];
  const float* c2sw=(const float*)d_in[18]; const float* c2sb=(const float*)d_in[19];
  const float* c2bw=(const float*)d_in[20]; const float* c2bb=(const float*)d_in[21];
  const float* g2w =(const float*)d_in[22]; const float* g2b =(const float*)d_in[23];
  const float* w1  =(const float*)d_in[24]; const float* b1v =(const float*)d_in[25];
  const float* w2  =(const float*)d_in[26]; const float* b2v =(const float*)d_in[27];

  // workspace layout (~36.6 MB total)
  float* wsf  = (float*)d_ws;
  float* Ag   = wsf;
  float* Bfg  = Ag   + 131072;
  float* Bbg  = Bfg  + 131072;
  float* Hf   = Bbg  + 131072;
  float* Hb   = Hf   + 131072;
  float* aff  = Hb   + 131072;       // 48 (pad 64)
  u16*   w1t  = (u16*)(aff + 64);    // 65536 u16, fragment-packed
  u16*   w2t  = w1t + 65536;         // 65536
  u16*   wot  = w2t + 65536;         // 32768
  u16*   wint = wot + 32768;         // 16384
  u16*   wit  = wint + 16384;
  u16*   wrt  = wit  + 16384;
  u32*   abg  = (u32*)(wrt + 16384); // [BSZ*SEQ*DIM] packed (a|b) = 33.5 MB

  float* outg = (float*)d_out;

  k_aff<<<dim3(1),dim3(64),0,stream>>>(c, c1sw,c1bw,g1w,c2sw,c2bw,g2w,
                                       c1sb,c1bb,g1b,c2sb,c2bb,g2b, aff);
  k_prep<<<dim3(104),dim3(256),0,stream>>>(w1,w2,wout,win,wi,wr,
                                           w1t,w2t,wot,wint,wit,wrt);
  k_pre<<<dim3(BSZ*NCH),dim3(256),0,stream>>>(x,wint,binv,pos,wit,biv,wrt,brv,av,aff,
                                              abg, Ag,Bfg,Bbg);
  k_chunkscan<<<dim3(16),dim3(128),0,stream>>>(Ag,Bfg,Bbg,Hf,Hb);
  k_scan<<<dim3(BSZ*NCH),dim3(256),0,stream>>>(abg,Hf,Hb,x,wot,bout,aff,outg);
  k_mlp<<<dim3(BSZ*NCH),dim3(256),0,stream>>>(w1t,b1v,w2t,b2v,aff,outg);
}

// Round 3
// 271.060 us; speedup vs baseline: 1.2999x; 1.1396x over previous
//
#include <hip/hip_runtime.h>
#include <hip/hip_bf16.h>

#define BSZ 8
#define SEQ 8192
#define DIM 128
#define NCH 128   // chunks per sequence
#define CLEN 64   // tokens per chunk

typedef unsigned short u16;
typedef unsigned int u32;
typedef short bf16x8 __attribute__((ext_vector_type(8)));
typedef float f32x4  __attribute__((ext_vector_type(4)));

__device__ __forceinline__ float us2f(u16 w){ union{u32 i;float f;}u; u.i=((u32)w)<<16; return u.f; }
__device__ __forceinline__ u16 f2us(float f){
  __hip_bfloat16 h = __float2bfloat16(f);
  union{ __hip_bfloat16 b; u16 s; }u; u.b=h; return u.s;
}
__device__ __forceinline__ float wred64(float v){
  #pragma unroll
  for (int o=1;o<64;o<<=1) v += __shfl_xor(v,o,64);
  return v;
}
__device__ __forceinline__ float red16(float v){
  v += __shfl_xor(v,1,64); v += __shfl_xor(v,2,64);
  v += __shfl_xor(v,4,64); v += __shfl_xor(v,8,64);
  return v;
}
__device__ __forceinline__ float sigmoidf_(float z){ return 1.f/(1.f+__expf(-z)); }
__device__ __forceinline__ float gelu_tanh(float x){
  float y = 0.7978845608028654f * fmaf(0.044715f*x, x*x, x);
  float e = __expf(2.f*y);
  float th = 1.f - 2.f/(e+1.f);
  return 0.5f*x*(1.f+th);
}
// wave-local LDS ordering: all prior ds ops complete before subsequent ones issue.
__device__ __forceinline__ void lds_fence(){
  asm volatile("s_waitcnt lgkmcnt(0)" ::: "memory");
  __builtin_amdgcn_sched_barrier(0);
}

// ---------------------------------------------------------------- K0: affines
__global__ __launch_bounds__(64) void k_aff(
    const float* __restrict__ c,
    const float* w0,const float* w1,const float* w2,const float* w3,const float* w4,const float* w5,
    const float* s0,const float* s1,const float* s2,const float* s3,const float* s4,const float* s5,
    float* __restrict__ aff)
{
  const float* ws[6]={w0,w1,w2,w3,w4,w5};
  const float* bs[6]={s0,s1,s2,s3,s4,s5};
  int l = threadIdx.x;
  for (int b=0;b<BSZ;++b){
    #pragma unroll
    for (int h=0;h<6;++h){
      float v = c[b*128+l]*ws[h][l] + c[b*128+64+l]*ws[h][64+l];
      v = wred64(v);
      if (l==0) aff[b*6+h] = v + bs[h][0];
    }
  }
}

// ---------------- K0b: pack weights into MFMA B-fragment-linear order (bf16)
__device__ __forceinline__ void pack_one(const float* __restrict__ W, int N,
                                         u16* __restrict__ out, int fi)
{
  int lane = fi & 63;
  int k2   = (fi >> 6) & 1;
  int cn   = fi >> 7;             // c*NB + n
  int NB   = N >> 4;
  int n    = cn % NB, c = cn / NB;
  int k0   = c*64 + k2*32 + (lane>>4)*8;
  int col  = n*16 + (lane&15);
  u16* o = out + (size_t)fi*8;
  #pragma unroll
  for (int j=0;j<8;++j) o[j] = f2us(W[(size_t)(k0+j)*N + col]);
}

__global__ __launch_bounds__(256) void k_prep(
    const float* __restrict__ w1, const float* __restrict__ w2, const float* __restrict__ wo,
    const float* __restrict__ win, const float* __restrict__ wi, const float* __restrict__ wr,
    u16* __restrict__ w1t, u16* __restrict__ w2t, u16* __restrict__ wot,
    u16* __restrict__ wint, u16* __restrict__ wit, u16* __restrict__ wrt)
{
  int i = blockIdx.x*256 + threadIdx.x;   // 104*256 = 26624 threads
  if      (i <  8192) pack_one(w1, 512, w1t, i);          // K=128,N=512
  else if (i < 16384) pack_one(w2, 128, w2t, i-8192);     // K=512,N=128
  else if (i < 20480) pack_one(wo, 128, wot, i-16384);    // K=256,N=128
  else if (i < 22528) pack_one(win,128, wint,i-20480);    // K=128,N=128
  else if (i < 24576) pack_one(wi, 128, wit, i-22528);
  else                pack_one(wr, 128, wrt, i-24576);
}

// -------------------- K1: LN + MFMA gates -> packed (a|b) + chunk summaries
// LDS: abp (32 KB) overlays A_l (17.4 KB) -> 5 blocks/CU by LDS.
// red16-style LN (4 rows per 16-lane group). abg written coalesced from LDS.
__global__ __launch_bounds__(256,4) void k_pre(
    const float* __restrict__ xg, const u16* __restrict__ wint, const float* __restrict__ b_in,
    const float* __restrict__ pos, const u16* __restrict__ wit, const float* __restrict__ b_i,
    const u16* __restrict__ wrt, const float* __restrict__ b_r, const float* __restrict__ avec,
    const float* __restrict__ aff,
    u32* __restrict__ abg,
    float* __restrict__ Ag, float* __restrict__ Bfg, float* __restrict__ Bbg)
{
  __shared__ __align__(16) u32 abp[CLEN*DIM];   // 32 KB; first phase aliased as A_l
  u16* A_l = (u16*)abp;                         // [64][136] = 17.4 KB
  const int t  = threadIdx.x;
  const int b  = blockIdx.x >> 7;
  const int ck = blockIdx.x & (NCH-1);
  const size_t base = ((size_t)(b*SEQ + ck*CLEN))*DIM;
  const int lane=t&63, wv=t>>6, col=lane&15, quad=lane>>4;
  const int m0 = wv*16;

  // LN: lnh = (x-m)*rs * s1p*rsqrt(s1p^2*vz + eps); 4 rows per 16-lane group
  {
    const float s1p = 1.f + aff[b*6+0];
    const int cg=t&15, rg=t>>4, j0=cg*8, r0=rg*4;
    #pragma unroll
    for (int ii=0;ii<4;++ii){
      int r=r0+ii;
      const float* xo = xg + base + (size_t)r*DIM + j0;
      float4 a = *(const float4*)xo;
      float4 bq = *(const float4*)(xo+4);
      float o[8]={a.x,a.y,a.z,a.w,bq.x,bq.y,bq.z,bq.w};
      float s=0.f;
      #pragma unroll
      for (int j=0;j<8;++j) s+=o[j];
      s=red16(s); float m=s*(1.f/128.f);
      float q2=0.f;
      #pragma unroll
      for (int j=0;j<8;++j){ float d=o[j]-m; q2+=d*d; }
      q2=red16(q2); float var=q2*(1.f/128.f);
      float rs=rsqrtf(var+1e-6f);
      float vz=var*rs*rs;
      float tt2=s1p*rsqrtf(fmaf(s1p*s1p,vz,1e-6f));
      float sc=rs*tt2;
      u32 pk[4];
      #pragma unroll
      for (int q=0;q<4;++q){
        pk[q]= (u32)f2us((o[2*q]-m)*sc) | ((u32)f2us((o[2*q+1]-m)*sc)<<16);
      }
      *(uint4*)&A_l[r*136+j0] = make_uint4(pk[0],pk[1],pk[2],pk[3]);
    }
  }
  lds_fence();   // LN writes (cross-lane, same wave) -> A reads

  // ---- mm B: u = lnh @ w_in (B direct from global, fragment-packed) ----
  f32x4 uacc[8];
  #pragma unroll
  for (int n=0;n<8;++n) uacc[n]=(f32x4){0.f,0.f,0.f,0.f};
  #pragma unroll
  for (int c=0;c<2;++c){
    #pragma unroll
    for (int k2=0;k2<2;++k2){
      bf16x8 av = *(const bf16x8*)&A_l[(m0+col)*136 + c*64 + k2*32 + quad*8];
      #pragma unroll
      for (int n=0;n<8;++n){
        bf16x8 bv = *(const bf16x8*)&wint[(size_t)(((c*8+n)*2+k2)*64+lane)*8];
        uacc[n] = __builtin_amdgcn_mfma_f32_16x16x32_bf16(av, bv, uacc[n], 0,0,0);
      }
    }
  }
  float u_c[8][4];
  #pragma unroll
  for (int n=0;n<8;++n){
    int nc = n*16 + col;
    float bi = b_in[nc];
    #pragma unroll
    for (int r=0;r<4;++r){
      int row = m0 + quad*4 + r;
      u_c[n][r] = uacc[n][r] + bi + pos[(size_t)(ck*CLEN+row)*DIM + nc];
    }
  }
  // write u (bf16) into A_l (own wave's 16-row stripe)
  #pragma unroll
  for (int n=0;n<8;++n){
    #pragma unroll
    for (int r=0;r<4;++r)
      A_l[(m0+quad*4+r)*136 + n*16+col] = f2us(u_c[n][r]);
  }
  lds_fence();   // u writes -> mm C/D A-reads (same wave)

  // ---- mm C+D fused: gi, gr (shared A-fragment reads) ----
  f32x4 gacc[8], racc[8];
  #pragma unroll
  for (int n=0;n<8;++n){ gacc[n]=(f32x4){0.f,0.f,0.f,0.f}; racc[n]=(f32x4){0.f,0.f,0.f,0.f}; }
  #pragma unroll
  for (int c=0;c<2;++c){
    #pragma unroll
    for (int k2=0;k2<2;++k2){
      bf16x8 av = *(const bf16x8*)&A_l[(m0+col)*136 + c*64 + k2*32 + quad*8];
      #pragma unroll
      for (int n=0;n<8;++n){
        bf16x8 bgi = *(const bf16x8*)&wit[(size_t)(((c*8+n)*2+k2)*64+lane)*8];
        gacc[n] = __builtin_amdgcn_mfma_f32_16x16x32_bf16(av, bgi, gacc[n], 0,0,0);
        bf16x8 bgr = *(const bf16x8*)&wrt[(size_t)(((c*8+n)*2+k2)*64+lane)*8];
        racc[n] = __builtin_amdgcn_mfma_f32_16x16x32_bf16(av, bgr, racc[n], 0,0,0);
      }
    }
  }
  __syncthreads();   // all A_l reads done -> safe to overwrite as abp

  // a_t, b_t -> packed LDS
  #pragma unroll
  for (int n=0;n<8;++n){
    int nc = n*16 + col;
    float la = __logf(avec[nc]);
    float br = b_r[nc];
    float bi = b_i[nc];
    #pragma unroll
    for (int r=0;r<4;++r){
      int row = m0 + quad*4 + r;
      float gi = sigmoidf_(gacc[n][r]+bi);
      float g  = sigmoidf_(racc[n][r]+br);
      float a  = __expf(8.f*g*la);
      float bb = sqrtf(fmaxf(1.f-a*a,0.f))*gi*u_c[n][r];
      abp[row*DIM+nc] = (u32)f2us(a) | ((u32)f2us(bb)<<16);
    }
  }
  __syncthreads();   // abp read cross-wave below

  // coalesced abg write (1 KB/wave-instr; kills the 2x write amplification)
  {
    uint4* dst = (uint4*)(abg + base);
    const uint4* src = (const uint4*)abp;
    #pragma unroll
    for (int i=t;i<2048;i+=256) dst[i]=src[i];
  }

  // chunk-local scans (over bf16 a,b -> consistent with k_scan) -> summaries
  const int sbase = (b*NCH+ck)*DIM;
  if (t < 128){
    float h=0.f, p=1.f;
    #pragma unroll 4
    for (int tt=0;tt<CLEN;++tt){
      u32 v=abp[tt*DIM+t];
      float a=us2f((u16)v), bb=us2f((u16)(v>>16));
      h=fmaf(a,h,bb); p*=a;
    }
    Ag[sbase+t]=p; Bfg[sbase+t]=h;
  } else {
    int ch=t-128; float h=0.f;
    #pragma unroll 4
    for (int tt=CLEN-1;tt>=0;--tt){
      u32 v=abp[tt*DIM+ch];
      h=fmaf(us2f((u16)v),h,us2f((u16)(v>>16)));
    }
    Bbg[sbase+ch]=h;
  }
}

// ------------------- K2: segmented prefix over chunk summaries (depth 16+8+16)
__global__ __launch_bounds__(1024) void k_chunkscan(
    const float* __restrict__ Ag, const float* __restrict__ Bfg, const float* __restrict__ Bbg,
    float* __restrict__ Hf, float* __restrict__ Hb)
{
  __shared__ float sP[8][128], sS[8][128];
  const int dir = blockIdx.x >> 3, b = blockIdx.x & 7;
  const int t = threadIdx.x, seg = t>>7, ch = t&127;
  const size_t cbase = (size_t)b*NCH*DIM + ch;
  float P=1.f, S=0.f;
  if (dir==0){
    #pragma unroll 4
    for (int j=0;j<16;++j){
      size_t i = cbase + (size_t)(seg*16+j)*DIM;
      float a=Ag[i]; S=fmaf(a,S,Bfg[i]); P*=a;
    }
  } else {
    #pragma unroll 4
    for (int j=15;j>=0;--j){
      size_t i = cbase + (size_t)(seg*16+j)*DIM;
      float a=Ag[i]; S=fmaf(a,S,Bbg[i]); P*=a;
    }
  }
  sP[seg][ch]=P; sS[seg][ch]=S;
  __syncthreads();
  float h=0.f;
  if (dir==0){ for (int s=0;s<seg;++s) h=fmaf(sP[s][ch],h,sS[s][ch]); }
  else       { for (int s=7;s>seg;--s) h=fmaf(sP[s][ch],h,sS[s][ch]); }
  if (dir==0){
    #pragma unroll 4
    for (int j=0;j<16;++j){
      size_t i = cbase + (size_t)(seg*16+j)*DIM;
      Hf[i]=h; h=fmaf(Ag[i],h,Bfg[i]);
    }
  } else {
    #pragma unroll 4
    for (int j=15;j>=0;--j){
      size_t i = cbase + (size_t)(seg*16+j)*DIM;
      Hb[i]=h; h=fmaf(Ag[i],h,Bbg[i]);
    }
  }
}

// -------------------- K3: seeded scan (direct-global, prefetched) + MFMA out-proj
// LDS: hcat only (33.8 KB -> 4 blocks/CU); C staged into dead hcat for
// fully coalesced residual read + output write.
__global__ __launch_bounds__(256,4) void k_scan(
    const u32* __restrict__ abg,
    const float* __restrict__ Hf, const float* __restrict__ Hb,
    const float* __restrict__ xg, const u16* __restrict__ wot, const float* __restrict__ b_out,
    const float* __restrict__ aff, float* __restrict__ outg)
{
  __shared__ __align__(16) u16 hcat[CLEN*264];    // 33.8 KB; later f32 C-tile
  const int t  = threadIdx.x;
  const int b  = blockIdx.x >> 7;
  const int ck = blockIdx.x & (NCH-1);
  const size_t base = ((size_t)(b*SEQ + ck*CLEN))*DIM;
  const int pbase=(b*NCH+ck)*DIM;

  // seeded scans straight from global with 4-deep prefetch -> hcat
  if (t<128){
    const u32* p = abg + base + t;
    float h = Hf[pbase+t];
    u32 v0=p[0], v1=p[128], v2=p[256], v3=p[384];
    #pragma unroll
    for (int g=0; g<16; ++g){
      u32 n0=0,n1=0,n2=0,n3=0;
      if (g<15){
        n0=p[(g*4+4)*128]; n1=p[(g*4+5)*128];
        n2=p[(g*4+6)*128]; n3=p[(g*4+7)*128];
      }
      h=fmaf(us2f((u16)v0),h,us2f((u16)(v0>>16))); hcat[(g*4+0)*264+t]=f2us(h);
      h=fmaf(us2f((u16)v1),h,us2f((u16)(v1>>16))); hcat[(g*4+1)*264+t]=f2us(h);
      h=fmaf(us2f((u16)v2),h,us2f((u16)(v2>>16))); hcat[(g*4+2)*264+t]=f2us(h);
      h=fmaf(us2f((u16)v3),h,us2f((u16)(v3>>16))); hcat[(g*4+3)*264+t]=f2us(h);
      v0=n0; v1=n1; v2=n2; v3=n3;
    }
  } else {
    int ch=t-128;
    const u32* p = abg + base + ch;
    float h = Hb[pbase+ch];
    u32 v0=p[63*128], v1=p[62*128], v2=p[61*128], v3=p[60*128];
    #pragma unroll
    for (int g=0; g<16; ++g){
      u32 n0=0,n1=0,n2=0,n3=0;
      if (g<15){
        n0=p[(59-g*4)*128]; n1=p[(58-g*4)*128];
        n2=p[(57-g*4)*128]; n3=p[(56-g*4)*128];
      }
      h=fmaf(us2f((u16)v0),h,us2f((u16)(v0>>16))); hcat[(63-g*4)*264+128+ch]=f2us(h);
      h=fmaf(us2f((u16)v1),h,us2f((u16)(v1>>16))); hcat[(62-g*4)*264+128+ch]=f2us(h);
      h=fmaf(us2f((u16)v2),h,us2f((u16)(v2>>16))); hcat[(61-g*4)*264+128+ch]=f2us(h);
      h=fmaf(us2f((u16)v3),h,us2f((u16)(v3>>16))); hcat[(60-g*4)*264+128+ch]=f2us(h);
      v0=n0; v1=n1; v2=n2; v3=n3;
    }
  }
  __syncthreads();

  // MFMA out-proj: C[64][128] = hcat[64][256] @ w_out[256][128]
  const int lane=t&63, wv=t>>6, col=lane&15, quad=lane>>4;
  const int m0 = wv*16;
  f32x4 acc[8];
  #pragma unroll
  for (int n=0;n<8;++n) acc[n]=(f32x4){0.f,0.f,0.f,0.f};
  #pragma unroll
  for (int chk=0; chk<4; ++chk){      // K-chunks of 64
    #pragma unroll
    for (int k2=0;k2<2;++k2){
      bf16x8 av = *(const bf16x8*)&hcat[(m0+col)*264 + chk*64 + k2*32 + quad*8];
      #pragma unroll
      for (int n=0;n<8;++n){
        bf16x8 bv = *(const bf16x8*)&wot[(size_t)(((chk*8+n)*2+k2)*64+lane)*8];
        acc[n] = __builtin_amdgcn_mfma_f32_16x16x32_bf16(av, bv, acc[n], 0,0,0);
      }
    }
  }
  __syncthreads();                // all hcat reads done -> overlay as f32 C
  float* pbuf = (float*)hcat;     // [64][128] f32 = 32 KB
  #pragma unroll
  for (int n=0;n<8;++n){
    #pragma unroll
    for (int r=0;r<4;++r)
      pbuf[(m0+quad*4+r)*128 + n*16+col] = acc[n][r];
  }
  __syncthreads();

  // fully coalesced residual + write
  const float g1=aff[b*6+2];
  const float4* xv4 = (const float4*)(xg+base);
  float4* ov4 = (float4*)(outg+base);
  const float4* cv4 = (const float4*)pbuf;
  #pragma unroll
  for (int i=t;i<2048;i+=256){
    float4 cv = cv4[i];
    float4 xv = xv4[i];
    float4 bo = *(const float4*)&b_out[(i*4)&127];
    float4 r;
    r.x=fmaf(g1,cv.x+bo.x,xv.x); r.y=fmaf(g1,cv.y+bo.y,xv.y);
    r.z=fmaf(g1,cv.z+bo.z,xv.z); r.w=fmaf(g1,cv.w+bo.w,xv.w);
    ov4[i]=r;
  }
}

// -------------------- K4: cLN2 + fused MFMA gelu MLP + gated residual
__global__ __launch_bounds__(256,2) void k_mlp(
    const u16* __restrict__ w1t, const float* __restrict__ b1v,
    const u16* __restrict__ w2t, const float* __restrict__ b2v,
    const float* __restrict__ aff, float* __restrict__ outg)
{
  __shared__ u16 smem[CLEN*136 + 4*2*16*136];   // 17408 + 17408 u16 = 34.8 KB
  u16* h2l = smem;                 // [64][136] LN output (A for mm1), cross-wave
  u16* m1t = smem + CLEN*136;      // per-wave: 2 tiles x [16][136] gelu scratch
  const int t=threadIdx.x;
  const int b=blockIdx.x>>7;
  const size_t base=(size_t)blockIdx.x*CLEN*DIM;
  const int lane=t&63, wv=t>>6, col=lane&15, quad=lane>>4;
  const float s2p=1.f+aff[b*6+3], b2a=aff[b*6+4], g2=aff[b*6+5];
  u16* mw = m1t + wv*(2*16*136);   // wave-private transpose scratch

  // step 0: h2 = (1+s2)*LN(x1)+b2 -> h2l (bf16)
  {
    const int cg=t&15, rg=t>>4, j0=cg*8, r0=rg*4;
    #pragma unroll
    for (int ii=0;ii<4;++ii){
      int r=r0+ii;
      const float* xo = outg + base + (size_t)r*DIM + j0;
      float4 a = *(const float4*)xo;
      float4 bq = *(const float4*)(xo+4);
      float o[8]={a.x,a.y,a.z,a.w,bq.x,bq.y,bq.z,bq.w};
      float s=0.f;
      #pragma unroll
      for (int j=0;j<8;++j) s+=o[j];
      s=red16(s); float m=s*(1.f/128.f);
      float q2=0.f;
      #pragma unroll
      for (int j=0;j<8;++j){ float d=o[j]-m; q2+=d*d; }
      q2=red16(q2); float rs=rsqrtf(q2*(1.f/128.f)+1e-6f);
      u32 pk[4];
      #pragma unroll
      for (int q=0;q<4;++q){
        float a0=fmaf((o[2*q]-m)*rs,   s2p, b2a);
        float a1=fmaf((o[2*q+1]-m)*rs, s2p, b2a);
        pk[q]= (u32)f2us(a0) | ((u32)f2us(a1)<<16);
      }
      *(uint4*)&h2l[r*136+j0] = make_uint4(pk[0],pk[1],pk[2],pk[3]);
    }
  }
  __syncthreads();   // h2l read cross-wave (all M-tiles by every wave)

  f32x4 acc2[4][8];  // full partial C2[64][128] for this wave's K-slice
  #pragma unroll
  for (int m=0;m<4;++m)
    #pragma unroll
    for (int n=0;n<8;++n) acc2[m][n]=(f32x4){0.f,0.f,0.f,0.f};

  #pragma unroll
  for (int mp=0;mp<2;++mp){           // M-tile pairs {0,1},{2,3}
    // ---- mm1: C1[pair rows][wave's 128 cols], n in 2 half-bursts of 4 ----
    #pragma unroll
    for (int h=0;h<2;++h){
      f32x4 a1[2][4];
      #pragma unroll
      for (int m=0;m<2;++m)
        #pragma unroll
        for (int n=0;n<4;++n) a1[m][n]=(f32x4){0.f,0.f,0.f,0.f};
      #pragma unroll
      for (int c=0;c<2;++c){
        #pragma unroll
        for (int k2=0;k2<2;++k2){
          bf16x8 av0 = *(const bf16x8*)&h2l[((2*mp+0)*16+col)*136 + c*64 + k2*32 + quad*8];
          bf16x8 av1 = *(const bf16x8*)&h2l[((2*mp+1)*16+col)*136 + c*64 + k2*32 + quad*8];
          #pragma unroll
          for (int n=0;n<4;++n){
            int ng = wv*8 + h*4 + n;   // global n-fragment (0..31)
            bf16x8 bv = *(const bf16x8*)&w1t[(size_t)(((c*32+ng)*2+k2)*64+lane)*8];
            a1[0][n] = __builtin_amdgcn_mfma_f32_16x16x32_bf16(av0, bv, a1[0][n], 0,0,0);
            a1[1][n] = __builtin_amdgcn_mfma_f32_16x16x32_bf16(av1, bv, a1[1][n], 0,0,0);
          }
        }
      }
      // prior mm2 reads of mw (previous pair) are done before overwrite
      lds_fence();
      // gelu + transpose into wave-private scratch (local cols 0..127)
      #pragma unroll
      for (int m=0;m<2;++m){
        #pragma unroll
        for (int n=0;n<4;++n){
          int lc = (h*4+n)*16 + col;           // local col 0..127
          float bb = b1v[wv*128 + lc];
          #pragma unroll
          for (int r=0;r<4;++r)
            mw[m*(16*136) + (quad*4+r)*136 + lc] = f2us(gelu_tanh(a1[m][n][r] + bb));
        }
      }
    }
    lds_fence();   // gelu writes -> mm2 A-reads (same wave)
    // ---- mm2 partial: acc2[pair] += m1[pair rows][wave K-slice] @ w2[slice][:]
    #pragma unroll
    for (int c2=0;c2<2;++c2){
      #pragma unroll
      for (int k2=0;k2<2;++k2){
        bf16x8 av0 = *(const bf16x8*)&mw[0*(16*136) + col*136 + c2*64 + k2*32 + quad*8];
        bf16x8 av1 = *(const bf16x8*)&mw[1*(16*136) + col*136 + c2*64 + k2*32 + quad*8];
        int cg = wv*2 + c2;                    // global K-chunk of w2 (0..7)
        #pragma unroll
        for (int n=0;n<8;++n){
          bf16x8 bv = *(const bf16x8*)&w2t[(size_t)(((cg*8+n)*2+k2)*64+lane)*8];
          acc2[2*mp+0][n] = __builtin_amdgcn_mfma_f32_16x16x32_bf16(av0, bv, acc2[2*mp+0][n], 0,0,0);
          acc2[2*mp+1][n] = __builtin_amdgcn_mfma_f32_16x16x32_bf16(av1, bv, acc2[2*mp+1][n], 0,0,0);
        }
      }
    }
  }
  __syncthreads();   // all mm2 done; smem is dead -> reuse as f32 pbuf

  // cross-wave K-reduction + epilogue, one M-tile (16 rows) per round
  float* pbuf = (float*)smem;        // [4 waves][16][128] f32 = 32 KB
  const int lrow = (lane>>4);        // 0..3
  const int cb   = (lane&15)*8;      // col block
  #pragma unroll
  for (int rt=0;rt<4;++rt){
    if (rt) __syncthreads();         // previous round's reads done
    #pragma unroll
    for (int n=0;n<8;++n){
      #pragma unroll
      for (int r=0;r<4;++r)
        pbuf[wv*2048 + (quad*4+r)*128 + n*16+col] = acc2[rt][n][r];
    }
    __syncthreads();
    // wave wv sums rows 4*wv..4*wv+3 of this tile across the 4 partials
    float s[8] = {0.f,0.f,0.f,0.f,0.f,0.f,0.f,0.f};
    #pragma unroll
    for (int p=0;p<4;++p){
      float4 x0 = *(const float4*)&pbuf[p*2048 + (4*wv+lrow)*128 + cb];
      float4 x1 = *(const float4*)&pbuf[p*2048 + (4*wv+lrow)*128 + cb + 4];
      s[0]+=x0.x; s[1]+=x0.y; s[2]+=x0.z; s[3]+=x0.w;
      s[4]+=x1.x; s[5]+=x1.y; s[6]+=x1.z; s[7]+=x1.w;
    }
    int grow = rt*16 + 4*wv + lrow;
    size_t gi = base + (size_t)grow*DIM + cb;
    float4 o0 = *(const float4*)&outg[gi];
    float4 o1 = *(const float4*)&outg[gi+4];
    float4 bb0 = *(const float4*)&b2v[cb];
    float4 bb1 = *(const float4*)&b2v[cb+4];
    float4 r0, r1;
    r0.x = fmaf(g2, s[0]+bb0.x, o0.x); r0.y = fmaf(g2, s[1]+bb0.y, o0.y);
    r0.z = fmaf(g2, s[2]+bb0.z, o0.z); r0.w = fmaf(g2, s[3]+bb0.w, o0.w);
    r1.x = fmaf(g2, s[4]+bb1.x, o1.x); r1.y = fmaf(g2, s[5]+bb1.y, o1.y);
    r1.z = fmaf(g2, s[6]+bb1.z, o1.z); r1.w = fmaf(g2, s[7]+bb1.w, o1.w);
    *(float4*)&outg[gi]   = r0;
    *(float4*)&outg[gi+4] = r1;
  }
}

// ----------------------------------------------------------------------------
extern "C" void kernel_launch(void* const* d_in, const int* in_sizes, int n_in,
                              void* d_out, int out_size, void* d_ws, size_t ws_size,
                              hipStream_t stream)
{
  (void)in_sizes; (void)n_in; (void)out_size; (void)ws_size;
  const float* x   =(const float*)d_in[0];
  const float* c   =(const float*)d_in[1];
  const float* c1sw=(const float*)d_in[2];  const float* c1sb=(const float*)d_in[3];
  const float* c1bw=(const float*)d_in[4];  const float* c1bb=(const float*)d_in[5];
  const float* g1w =(const float*)d_in[6];  const float* g1b =(const float*)d_in[7];
  const float* win =(const float*)d_in[8];  const float* binv=(const float*)d_in[9];
  const float* pos =(const float*)d_in[10];
  const float* wi  =(const float*)d_in[11]; const float* biv =(const float*)d_in[12];
  const float* wr  =(const float*)d_in[13]; const float* brv =(const float*)d_in[14];
  const float* av  =(const float*)d_in[15];
  const float* wout=(const float*)d_in[16]; const float* bout=(const float*)d_in[17];
  const float* c2sw=(const float*)d_in[18]; const float* c2sb=(const float*)d_in[19];
  const float* c2bw=(const float*)d_in[20]; const float* c2bb=(const float*)d_in[21];
  const float* g2w =(const float*)d_in[22]; const float* g2b =(const float*)d_in[23];
  const float* w1  =(const float*)d_in[24]; const float* b1v =(const float*)d_in[25];
  const float* w2  =(const float*)d_in[26]; const float* b2v =(const float*)d_in[27];

  // workspace layout (~36.6 MB total)
  float* wsf  = (float*)d_ws;
  float* Ag   = wsf;
  float* Bfg  = Ag   + 131072;
  float* Bbg  = Bfg  + 131072;
  float* Hf   = Bbg  + 131072;
  float* Hb   = Hf   + 131072;
  float* aff  = Hb   + 131072;       // 48 (pad 64)
  u16*   w1t  = (u16*)(aff + 64);    // 65536 u16, fragment-packed
  u16*   w2t  = w1t + 65536;         // 65536
  u16*   wot  = w2t + 65536;         // 32768
  u16*   wint = wot + 32768;         // 16384
  u16*   wit  = wint + 16384;
  u16*   wrt  = wit  + 16384;
  u32*   abg  = (u32*)(wrt + 16384); // [BSZ*SEQ*DIM] packed (a|b) = 33.5 MB

  float* outg = (float*)d_out;

  k_aff<<<dim3(1),dim3(64),0,stream>>>(c, c1sw,c1bw,g1w,c2sw,c2bw,g2w,
                                       c1sb,c1bb,g1b,c2sb,c2bb,g2b, aff);
  k_prep<<<dim3(104),dim3(256),0,stream>>>(w1,w2,wout,win,wi,wr,
                                           w1t,w2t,wot,wint,wit,wrt);
  k_pre<<<dim3(BSZ*NCH),dim3(256),0,stream>>>(x,wint,binv,pos,wit,biv,wrt,brv,av,aff,
                                              abg, Ag,Bfg,Bbg);
  k_chunkscan<<<dim3(16),dim3(1024),0,stream>>>(Ag,Bfg,Bbg,Hf,Hb);
  k_scan<<<dim3(BSZ*NCH),dim3(256),0,stream>>>(abg,Hf,Hb,x,wot,bout,aff,outg);
  k_mlp<<<dim3(BSZ*NCH),dim3(256),0,stream>>>(w1t,b1v,w2t,b2v,aff,outg);
}